// Round 5
// baseline (696.752 us; speedup 1.0000x reference)
//
#include <hip/hip_runtime.h>

#define N_NODES 100000
#define N_EDGES 400000
#define D 128
#define BN_EPS 1e-5f

typedef short short8 __attribute__((ext_vector_type(8)));   // 8 bf16 as raw shorts (4 VGPRs)
typedef float f32x4 __attribute__((ext_vector_type(4)));

static __device__ __forceinline__ float bf2f(unsigned short u) {
    unsigned x = ((unsigned)u) << 16;
    return __builtin_bit_cast(float, x);
}
static __device__ __forceinline__ unsigned short f2bf(float f) {
    unsigned x = __builtin_bit_cast(unsigned, f);
    x += 0x7fffu + ((x >> 16) & 1u);   // round-to-nearest-even
    return (unsigned short)(x >> 16);
}
// split f32 into bf16 hi + bf16 lo (a ~= hi + lo, residual ~2^-17 rel)
static __device__ __forceinline__ void splitbf(float a, short& hi, short& lo) {
    unsigned short h = f2bf(a);
    float r = a - bf2f(h);
    hi = (short)h;
    lo = (short)f2bf(r);
}

// ---------------------------------------------------------------- fallback: clean zero-fill of d_out
__global__ void k_zero_out(float* __restrict__ y, int n4) {
    int t = blockIdx.x * blockDim.x + threadIdx.x;
    if (t < n4) ((float4*)y)[t] = float4{0.f, 0.f, 0.f, 0.f};
}

// ---------------------------------------------------------------- degrees
__global__ void k_degrees(const int* __restrict__ src, const int* __restrict__ dst,
                          float* __restrict__ outdeg, float* __restrict__ indeg) {
    int t = blockIdx.x * blockDim.x + threadIdx.x;
    if (t >= N_EDGES) return;
    unsafeAtomicAdd(&outdeg[src[t]], 1.0f);
    unsafeAtomicAdd(&indeg[dst[t]], 1.0f);
}

// ---------------------------------------------------------------- rsqrt of degrees
__global__ void k_coeffs(const float* __restrict__ outdeg, const float* __restrict__ indeg,
                         float* __restrict__ c_src, float* __restrict__ c_dst) {
    int t = blockIdx.x * blockDim.x + threadIdx.x;
    if (t >= N_NODES) return;
    c_src[t] = rsqrtf(fmaxf(outdeg[t], 1.0f));
    c_dst[t] = rsqrtf(fmaxf(indeg[t], 1.0f));
}

// ---------------------------------------------------------------- edge scatter-add (f32)
// one wave per edge; lane handles 2 features (float2 load, 2 f32 atomics)
__global__ void k_scatter(const float* __restrict__ x,
                          const int* __restrict__ src, const int* __restrict__ dst,
                          const float* __restrict__ c_src, float* __restrict__ agg) {
    int e = blockIdx.x * 4 + (threadIdx.x >> 6);
    if (e >= N_EDGES) return;
    int lane = threadIdx.x & 63;
    int s = src[e], d = dst[e];
    float c = c_src[s];
    float2 pk = ((const float2*)(x + (size_t)s * D))[lane];
    float* out = agg + (size_t)d * D + lane * 2;
    unsafeAtomicAdd(out, pk.x * c);
    unsafeAtomicAdd(out + 1, pk.y * c);
}

// ---------------------------------------------------------------- W(f32) -> MFMA B-fragment order, split hi/lo bf16
// frag layout: fragIdx = ntile*4 + kstep; element j of lane l = W[kstep*32 + (l>>4)*8 + j][ntile*16 + (l&15)]
__global__ void k_make_frags(const float* __restrict__ W,
                             const float* __restrict__ Wr,
                             unsigned short* __restrict__ Whi, unsigned short* __restrict__ Wlo,
                             unsigned short* __restrict__ Wrhi, unsigned short* __restrict__ Wrlo) {
    int t = blockIdx.x * blockDim.x + threadIdx.x;   // 0..4095
    if (t >= 4096) return;
    int mat = t >> 11;
    int fragIdx = (t >> 6) & 31;
    int lane = t & 63;
    int nt = fragIdx >> 2, ks = fragIdx & 3;
    const float* Wsrc = mat ? Wr : W;
    unsigned short* dhi = mat ? Wrhi : Whi;
    unsigned short* dlo = mat ? Wrlo : Wlo;
    int n = nt * 16 + (lane & 15);
    int kbase = ks * 32 + (lane >> 4) * 8;
    short hi[8], lo[8];
#pragma unroll
    for (int j = 0; j < 8; j++) splitbf(Wsrc[(kbase + j) * D + n], hi[j], lo[j]);
    ((uint4*)dhi)[fragIdx * 64 + lane] = *(uint4*)hi;
    ((uint4*)dlo)[fragIdx * 64 + lane] = *(uint4*)lo;
}

// ---------------------------------------------------------------- GEMM pass: y = relu(A*rs @ W + bias) [+ prev, + BN stats]
// bf16x3 split-precision MFMA: acc += Ahi*Whi + Ahi*Wlo + Alo*Whi
__global__ __launch_bounds__(256, 2) void k_gemm_pass(
    const float* __restrict__ A,         // [N,128] f32 (agg or node_feats)
    const float* __restrict__ rowscale,  // c_dst or nullptr
    const unsigned short* __restrict__ Whi, const unsigned short* __restrict__ Wlo,
    const float* __restrict__ bias,
    float* __restrict__ yio,             // d_out (f32)
    int addPrev,                         // 0: yio = relu(..); 1: yio += relu(..), collect stats
    float* __restrict__ gsum, float* __restrict__ gsq,
    int nRowTiles) {
    __shared__ uint4 ldsHi[2048];   // 32 KB
    __shared__ uint4 ldsLo[2048];   // 32 KB
    {
        const uint4* gh = (const uint4*)Whi;
        const uint4* gl = (const uint4*)Wlo;
        for (int i = threadIdx.x; i < 2048; i += 256) {
            ldsHi[i] = gh[i];
            ldsLo[i] = gl[i];
        }
    }
    __syncthreads();

    const int wave = threadIdx.x >> 6;
    const int lane = threadIdx.x & 63;
    const int quad = lane >> 4;
    const int l16 = lane & 15;
    const int gwid = blockIdx.x * 4 + wave;
    const int nWaves = gridDim.x * 4;

    float s_acc[8], q_acc[8];
#pragma unroll
    for (int i = 0; i < 8; i++) { s_acc[i] = 0.f; q_acc[i] = 0.f; }

    for (int rt = gwid; rt < nRowTiles; rt += nWaves) {
        const int rowbase = rt * 16;
        const int arow = rowbase + l16;
        const float rs = rowscale ? rowscale[arow] : 1.0f;

        // ---- build split A fragments: lane l16 = row m, k = ks*32 + quad*8 + j
        short8 ahi[4], alo[4];
        const float4* ap = (const float4*)(A + (size_t)arow * D + quad * 8);
#pragma unroll
        for (int ks = 0; ks < 4; ks++) {
            float4 f0 = ap[ks * 8];       // k = ks*32+quad*8 .. +3
            float4 f1 = ap[ks * 8 + 1];   // k = +4 .. +7
            float v[8] = {f0.x, f0.y, f0.z, f0.w, f1.x, f1.y, f1.z, f1.w};
            short8 h, l;
#pragma unroll
            for (int j = 0; j < 8; j++) {
                short hh, ll;
                splitbf(v[j] * rs, hh, ll);
                h[j] = hh; l[j] = ll;
            }
            ahi[ks] = h; alo[ks] = l;
        }

#pragma unroll
        for (int nt = 0; nt < 8; nt++) {
            f32x4 acc = {0.f, 0.f, 0.f, 0.f};
#pragma unroll
            for (int ks = 0; ks < 4; ks++) {
                short8 wh = __builtin_bit_cast(short8, ldsHi[(nt * 4 + ks) * 64 + lane]);
                short8 wl = __builtin_bit_cast(short8, ldsLo[(nt * 4 + ks) * 64 + lane]);
                acc = __builtin_amdgcn_mfma_f32_16x16x32_bf16(ahi[ks], wh, acc, 0, 0, 0);
                acc = __builtin_amdgcn_mfma_f32_16x16x32_bf16(ahi[ks], wl, acc, 0, 0, 0);
                acc = __builtin_amdgcn_mfma_f32_16x16x32_bf16(alo[ks], wh, acc, 0, 0, 0);
            }
            const int col = nt * 16 + l16;
            const float bz = bias[col];
            float s = 0.f, q = 0.f;
#pragma unroll
            for (int r = 0; r < 4; r++) {
                int row = rowbase + quad * 4 + r;
                size_t idx = (size_t)row * D + col;
                float v = fmaxf(acc[r] + bz, 0.f);
                if (addPrev) {
                    float y = yio[idx] + v;
                    yio[idx] = y;
                    s += y;
                    q += y * y;
                } else {
                    yio[idx] = v;
                }
            }
            s_acc[nt] += s;
            q_acc[nt] += q;
        }
    }

    if (addPrev) {
#pragma unroll
        for (int nt = 0; nt < 8; nt++) {
            float s = s_acc[nt], q = q_acc[nt];
            s += __shfl_xor(s, 16, 64);
            s += __shfl_xor(s, 32, 64);
            q += __shfl_xor(q, 16, 64);
            q += __shfl_xor(q, 32, 64);
            if (lane < 16) {
                unsafeAtomicAdd(&gsum[nt * 16 + lane], s);
                unsafeAtomicAdd(&gsq[nt * 16 + lane], q);
            }
        }
    }
}

// ---------------------------------------------------------------- BN stats -> scale/shift (f32)
__global__ void k_bn_stats(const float* __restrict__ gsum, const float* __restrict__ gsq,
                           const float* __restrict__ gamma, const float* __restrict__ beta,
                           float* __restrict__ scale, float* __restrict__ shift) {
    int f = threadIdx.x;   // 128 threads
    const float invN = 1.0f / (float)N_NODES;
    float mean = gsum[f] * invN;
    float var = fmaxf(gsq[f] * invN - mean * mean, 0.f);
    float sc = gamma[f] * rsqrtf(var + BN_EPS);
    scale[f] = sc;
    shift[f] = beta[f] - mean * sc;
}

// ---------------------------------------------------------------- apply BN in-place on d_out (f32)
__global__ void k_bn_apply(float* __restrict__ y,
                           const float* __restrict__ scale, const float* __restrict__ shift) {
    int t = blockIdx.x * blockDim.x + threadIdx.x;
    const int total4 = N_NODES * D / 4;
    if (t >= total4) return;
    float4 v = ((float4*)y)[t];
    int f = (t * 4) & (D - 1);
    v.x = v.x * scale[f] + shift[f];
    v.y = v.y * scale[f + 1] + shift[f + 1];
    v.z = v.z * scale[f + 2] + shift[f + 2];
    v.w = v.w * scale[f + 3] + shift[f + 3];
    ((float4*)y)[t] = v;
}

// ---------------------------------------------------------------- launch
extern "C" void kernel_launch(void* const* d_in, const int* in_sizes, int n_in,
                              void* d_out, int out_size, void* d_ws, size_t ws_size,
                              hipStream_t stream) {
    const float* x     = (const float*)d_in[0];   // node_feats f32 [N,128]
    const float* W     = (const float*)d_in[1];
    const float* b     = (const float*)d_in[2];
    const float* Wr    = (const float*)d_in[3];
    const float* br    = (const float*)d_in[4];
    const float* gamma = (const float*)d_in[5];
    const float* beta  = (const float*)d_in[6];
    const int* src = (const int*)d_in[7];
    const int* dst = (const int*)d_in[8];
    float* out = (float*)d_out;

    char* ws = (char*)d_ws;
    size_t off = 0;
    // ---- zeroed prefix (one contiguous memset) ----
    float* gsum   = (float*)(ws + off); off += 512;
    float* gsq    = (float*)(ws + off); off += 512;
    float* outdeg = (float*)(ws + off); off += (size_t)N_NODES * 4;
    float* indeg  = (float*)(ws + off); off += (size_t)N_NODES * 4;
    float* agg    = (float*)(ws + off); off += (size_t)N_NODES * D * 4;  // 51.2 MB
    const size_t zero_bytes = off;
    // ---- non-zeroed scratch ----
    float* c_src  = (float*)(ws + off); off += (size_t)N_NODES * 4;
    float* c_dst  = (float*)(ws + off); off += (size_t)N_NODES * 4;
    unsigned short* WhiF  = (unsigned short*)(ws + off); off += 32768;
    unsigned short* WloF  = (unsigned short*)(ws + off); off += 32768;
    unsigned short* WrhiF = (unsigned short*)(ws + off); off += 32768;
    unsigned short* WrloF = (unsigned short*)(ws + off); off += 32768;
    float* scale = (float*)(ws + off); off += 512;
    float* shift = (float*)(ws + off); off += 512;
    const size_t needed = off;

    if (ws_size < needed) {
        k_zero_out<<<(N_NODES * D / 4 + 255) / 256, 256, 0, stream>>>(out, N_NODES * D / 4);
        return;
    }

    hipMemsetAsync(d_ws, 0, zero_bytes, stream);

    k_make_frags<<<16, 256, 0, stream>>>(W, Wr, WhiF, WloF, WrhiF, WrloF);
    k_degrees<<<(N_EDGES + 255) / 256, 256, 0, stream>>>(src, dst, outdeg, indeg);
    k_coeffs<<<(N_NODES + 255) / 256, 256, 0, stream>>>(outdeg, indeg, c_src, c_dst);
    k_scatter<<<(N_EDGES + 3) / 4, 256, 0, stream>>>(x, src, dst, c_src, agg);
    // pass 1: d_out = relu(agg*c_dst @ W + b)
    k_gemm_pass<<<512, 256, 0, stream>>>(agg, c_dst, WhiF, WloF, b, out, 0,
                                         (float*)nullptr, (float*)nullptr, N_NODES / 16);
    // pass 2: d_out += relu(x @ Wr + br), collect BN stats
    k_gemm_pass<<<512, 256, 0, stream>>>(x, (const float*)nullptr, WrhiF, WrloF, br, out, 1,
                                         gsum, gsq, N_NODES / 16);
    k_bn_stats<<<1, 128, 0, stream>>>(gsum, gsq, gamma, beta, scale, shift);
    k_bn_apply<<<(N_NODES * D / 4 + 255) / 256, 256, 0, stream>>>(out, scale, shift);
}

// Round 6
// 453.612 us; speedup vs baseline: 1.5360x; 1.5360x over previous
//
#include <hip/hip_runtime.h>

#define N_NODES 100000
#define N_EDGES 400000
#define D 128
#define BN_EPS 1e-5f

typedef short short8 __attribute__((ext_vector_type(8)));   // 8 bf16 as raw shorts (4 VGPRs)
typedef float f32x4 __attribute__((ext_vector_type(4)));

static __device__ __forceinline__ float bf2f(unsigned short u) {
    unsigned x = ((unsigned)u) << 16;
    return __builtin_bit_cast(float, x);
}
static __device__ __forceinline__ unsigned short f2bf(float f) {
    unsigned x = __builtin_bit_cast(unsigned, f);
    x += 0x7fffu + ((x >> 16) & 1u);   // round-to-nearest-even
    return (unsigned short)(x >> 16);
}
// split f32 into bf16 hi + bf16 lo (a ~= hi + lo, residual ~2^-17 rel)
static __device__ __forceinline__ void splitbf(float a, short& hi, short& lo) {
    unsigned short h = f2bf(a);
    float r = a - bf2f(h);
    hi = (short)h;
    lo = (short)f2bf(r);
}

// ---------------------------------------------------------------- fallback: clean zero-fill of d_out
__global__ void k_zero_out(float* __restrict__ y, int n4) {
    int t = blockIdx.x * blockDim.x + threadIdx.x;
    if (t < n4) ((float4*)y)[t] = float4{0.f, 0.f, 0.f, 0.f};
}

// ---------------------------------------------------------------- degree histograms
__global__ void k_count(const int* __restrict__ src, const int* __restrict__ dst,
                        int* __restrict__ cnt_src, int* __restrict__ cnt_dst) {
    int t = blockIdx.x * blockDim.x + threadIdx.x;
    if (t >= N_EDGES) return;
    atomicAdd(&cnt_src[src[t]], 1);
    atomicAdd(&cnt_dst[dst[t]], 1);
}

// ---------------------------------------------------------------- rsqrt coeffs (+ zero the fill cursors)
__global__ void k_coeffs(const int* __restrict__ cnt_src, const int* __restrict__ cnt_dst,
                         float* __restrict__ c_src, float* __restrict__ c_dst,
                         int* __restrict__ fill) {
    int t = blockIdx.x * blockDim.x + threadIdx.x;
    if (t >= N_NODES) return;
    c_src[t] = rsqrtf(fmaxf((float)cnt_src[t], 1.0f));
    c_dst[t] = rsqrtf(fmaxf((float)cnt_dst[t], 1.0f));
    fill[t] = 0;
}

// ---------------------------------------------------------------- exclusive scan, level 1 (256/block)
__global__ void k_scan1(const int* __restrict__ cnt, int* __restrict__ outp,
                        int* __restrict__ bsum) {
    __shared__ int s[256];
    int i = blockIdx.x * 256 + threadIdx.x;
    int v = (i < N_NODES) ? cnt[i] : 0;
    s[threadIdx.x] = v;
    __syncthreads();
    for (int d = 1; d < 256; d <<= 1) {
        int t = (threadIdx.x >= d) ? s[threadIdx.x - d] : 0;
        __syncthreads();
        s[threadIdx.x] += t;
        __syncthreads();
    }
    if (i < N_NODES) outp[i] = s[threadIdx.x] - v;   // exclusive
    if (threadIdx.x == 255) bsum[blockIdx.x] = s[255];
}

// ---------------------------------------------------------------- exclusive scan, level 2 (single block, nb<=512)
__global__ void k_scan2(int* __restrict__ bsum, int nb) {
    __shared__ int s[512];
    int v = (threadIdx.x < nb) ? bsum[threadIdx.x] : 0;
    s[threadIdx.x] = v;
    __syncthreads();
    for (int d = 1; d < 512; d <<= 1) {
        int t = (threadIdx.x >= d) ? s[threadIdx.x - d] : 0;
        __syncthreads();
        s[threadIdx.x] += t;
        __syncthreads();
    }
    if (threadIdx.x < nb) bsum[threadIdx.x] = s[threadIdx.x] - v;
}

// ---------------------------------------------------------------- scan fixup
__global__ void k_scan3(int* __restrict__ rowStart, const int* __restrict__ boff) {
    int i = blockIdx.x * 256 + threadIdx.x;
    if (i < N_NODES) rowStart[i] += boff[i >> 8];
    if (i == 0) rowStart[N_NODES] = N_EDGES;
}

// ---------------------------------------------------------------- bucket-fill: edge srcs sorted by dst
__global__ void k_fill(const int* __restrict__ src, const int* __restrict__ dst,
                       const int* __restrict__ rowStart, int* __restrict__ fill,
                       int* __restrict__ esorted) {
    int e = blockIdx.x * blockDim.x + threadIdx.x;
    if (e >= N_EDGES) return;
    int d = dst[e];
    int pos = rowStart[d] + atomicAdd(&fill[d], 1);
    esorted[pos] = src[e];
}

// ---------------------------------------------------------------- segmented gather: one wave per node
// agg[n] = c_dst[n] * sum_{e: dst=n} c_src[src_e] * x[src_e]   (written once, no atomics)
__global__ void k_gather(const float* __restrict__ x,
                         const int* __restrict__ esorted, const int* __restrict__ rowStart,
                         const float* __restrict__ c_src, const float* __restrict__ c_dst,
                         float* __restrict__ agg) {
    int n = blockIdx.x * 4 + (threadIdx.x >> 6);
    if (n >= N_NODES) return;
    int lane = threadIdx.x & 63;
    int beg = rowStart[n], end = rowStart[n + 1];
    float a0 = 0.f, a1 = 0.f;
    for (int j = beg; j < end; j++) {
        int s = esorted[j];
        float c = c_src[s];
        float2 pk = ((const float2*)(x + (size_t)s * D))[lane];
        a0 += pk.x * c;
        a1 += pk.y * c;
    }
    float cd = c_dst[n];
    ((float2*)(agg + (size_t)n * D))[lane] = float2{a0 * cd, a1 * cd};
}

// ---------------------------------------------------------------- W(f32) -> MFMA B-fragment order, split hi/lo bf16
// frag layout: fragIdx = ntile*4 + kstep; element j of lane l = W[kstep*32 + (l>>4)*8 + j][ntile*16 + (l&15)]
__global__ void k_make_frags(const float* __restrict__ W,
                             const float* __restrict__ Wr,
                             unsigned short* __restrict__ Whi, unsigned short* __restrict__ Wlo,
                             unsigned short* __restrict__ Wrhi, unsigned short* __restrict__ Wrlo) {
    int t = blockIdx.x * blockDim.x + threadIdx.x;   // 0..4095
    if (t >= 4096) return;
    int mat = t >> 11;
    int fragIdx = (t >> 6) & 31;
    int lane = t & 63;
    int nt = fragIdx >> 2, ks = fragIdx & 3;
    const float* Wsrc = mat ? Wr : W;
    unsigned short* dhi = mat ? Wrhi : Whi;
    unsigned short* dlo = mat ? Wrlo : Wlo;
    int n = nt * 16 + (lane & 15);
    int kbase = ks * 32 + (lane >> 4) * 8;
    short hi[8], lo[8];
#pragma unroll
    for (int j = 0; j < 8; j++) splitbf(Wsrc[(kbase + j) * D + n], hi[j], lo[j]);
    ((uint4*)dhi)[fragIdx * 64 + lane] = *(uint4*)hi;
    ((uint4*)dlo)[fragIdx * 64 + lane] = *(uint4*)lo;
}

// ---------------------------------------------------------------- GEMM pass: y = relu(A*rs @ W + bias) [+ prev, + BN stats]
// bf16x3 split-precision MFMA: acc += Ahi*Whi + Ahi*Wlo + Alo*Whi
__global__ __launch_bounds__(256, 2) void k_gemm_pass(
    const float* __restrict__ A,         // [N,128] f32 (agg or node_feats)
    const float* __restrict__ rowscale,  // c_dst or nullptr
    const unsigned short* __restrict__ Whi, const unsigned short* __restrict__ Wlo,
    const float* __restrict__ bias,
    float* __restrict__ yio,             // d_out (f32)
    int addPrev,                         // 0: yio = relu(..); 1: yio += relu(..), collect stats
    float* __restrict__ gsum, float* __restrict__ gsq,
    int nRowTiles) {
    __shared__ uint4 ldsHi[2048];   // 32 KB
    __shared__ uint4 ldsLo[2048];   // 32 KB
    {
        const uint4* gh = (const uint4*)Whi;
        const uint4* gl = (const uint4*)Wlo;
        for (int i = threadIdx.x; i < 2048; i += 256) {
            ldsHi[i] = gh[i];
            ldsLo[i] = gl[i];
        }
    }
    __syncthreads();

    const int wave = threadIdx.x >> 6;
    const int lane = threadIdx.x & 63;
    const int quad = lane >> 4;
    const int l16 = lane & 15;
    const int gwid = blockIdx.x * 4 + wave;
    const int nWaves = gridDim.x * 4;

    float s_acc[8], q_acc[8];
#pragma unroll
    for (int i = 0; i < 8; i++) { s_acc[i] = 0.f; q_acc[i] = 0.f; }

    for (int rt = gwid; rt < nRowTiles; rt += nWaves) {
        const int rowbase = rt * 16;
        const int arow = rowbase + l16;
        const float rs = rowscale ? rowscale[arow] : 1.0f;

        // ---- build split A fragments: lane l16 = row m, k = ks*32 + quad*8 + j
        short8 ahi[4], alo[4];
        const float4* ap = (const float4*)(A + (size_t)arow * D + quad * 8);
#pragma unroll
        for (int ks = 0; ks < 4; ks++) {
            float4 f0 = ap[ks * 8];       // k = ks*32+quad*8 .. +3
            float4 f1 = ap[ks * 8 + 1];   // k = +4 .. +7
            float v[8] = {f0.x, f0.y, f0.z, f0.w, f1.x, f1.y, f1.z, f1.w};
            short8 h, l;
#pragma unroll
            for (int j = 0; j < 8; j++) {
                short hh, ll;
                splitbf(v[j] * rs, hh, ll);
                h[j] = hh; l[j] = ll;
            }
            ahi[ks] = h; alo[ks] = l;
        }

#pragma unroll
        for (int nt = 0; nt < 8; nt++) {
            f32x4 acc = {0.f, 0.f, 0.f, 0.f};
#pragma unroll
            for (int ks = 0; ks < 4; ks++) {
                short8 wh = __builtin_bit_cast(short8, ldsHi[(nt * 4 + ks) * 64 + lane]);
                short8 wl = __builtin_bit_cast(short8, ldsLo[(nt * 4 + ks) * 64 + lane]);
                acc = __builtin_amdgcn_mfma_f32_16x16x32_bf16(ahi[ks], wh, acc, 0, 0, 0);
                acc = __builtin_amdgcn_mfma_f32_16x16x32_bf16(ahi[ks], wl, acc, 0, 0, 0);
                acc = __builtin_amdgcn_mfma_f32_16x16x32_bf16(alo[ks], wh, acc, 0, 0, 0);
            }
            const int col = nt * 16 + l16;
            const float bz = bias[col];
            float s = 0.f, q = 0.f;
#pragma unroll
            for (int r = 0; r < 4; r++) {
                int row = rowbase + quad * 4 + r;
                size_t idx = (size_t)row * D + col;
                float v = fmaxf(acc[r] + bz, 0.f);
                if (addPrev) {
                    float y = yio[idx] + v;
                    yio[idx] = y;
                    s += y;
                    q += y * y;
                } else {
                    yio[idx] = v;
                }
            }
            s_acc[nt] += s;
            q_acc[nt] += q;
        }
    }

    if (addPrev) {
#pragma unroll
        for (int nt = 0; nt < 8; nt++) {
            float s = s_acc[nt], q = q_acc[nt];
            s += __shfl_xor(s, 16, 64);
            s += __shfl_xor(s, 32, 64);
            q += __shfl_xor(q, 16, 64);
            q += __shfl_xor(q, 32, 64);
            if (lane < 16) {
                unsafeAtomicAdd(&gsum[nt * 16 + lane], s);
                unsafeAtomicAdd(&gsq[nt * 16 + lane], q);
            }
        }
    }
}

// ---------------------------------------------------------------- BN stats -> scale/shift (f32)
__global__ void k_bn_stats(const float* __restrict__ gsum, const float* __restrict__ gsq,
                           const float* __restrict__ gamma, const float* __restrict__ beta,
                           float* __restrict__ scale, float* __restrict__ shift) {
    int f = threadIdx.x;   // 128 threads
    const float invN = 1.0f / (float)N_NODES;
    float mean = gsum[f] * invN;
    float var = fmaxf(gsq[f] * invN - mean * mean, 0.f);
    float sc = gamma[f] * rsqrtf(var + BN_EPS);
    scale[f] = sc;
    shift[f] = beta[f] - mean * sc;
}

// ---------------------------------------------------------------- apply BN in-place on d_out (f32)
__global__ void k_bn_apply(float* __restrict__ y,
                           const float* __restrict__ scale, const float* __restrict__ shift) {
    int t = blockIdx.x * blockDim.x + threadIdx.x;
    const int total4 = N_NODES * D / 4;
    if (t >= total4) return;
    float4 v = ((float4*)y)[t];
    int f = (t * 4) & (D - 1);
    v.x = v.x * scale[f] + shift[f];
    v.y = v.y * scale[f + 1] + shift[f + 1];
    v.z = v.z * scale[f + 2] + shift[f + 2];
    v.w = v.w * scale[f + 3] + shift[f + 3];
    ((float4*)y)[t] = v;
}

// ---------------------------------------------------------------- launch
extern "C" void kernel_launch(void* const* d_in, const int* in_sizes, int n_in,
                              void* d_out, int out_size, void* d_ws, size_t ws_size,
                              hipStream_t stream) {
    const float* x     = (const float*)d_in[0];   // node_feats f32 [N,128]
    const float* W     = (const float*)d_in[1];
    const float* b     = (const float*)d_in[2];
    const float* Wr    = (const float*)d_in[3];
    const float* br    = (const float*)d_in[4];
    const float* gamma = (const float*)d_in[5];
    const float* beta  = (const float*)d_in[6];
    const int* src = (const int*)d_in[7];
    const int* dst = (const int*)d_in[8];
    float* out = (float*)d_out;

    const int NB1 = (N_NODES + 255) / 256;   // 391 scan blocks

    char* ws = (char*)d_ws;
    size_t off = 0;
    // ---- zeroed prefix (one contiguous memset, ~0.8 MB) ----
    float* gsum    = (float*)(ws + off); off += 512;
    float* gsq     = (float*)(ws + off); off += 512;
    int* cnt_src   = (int*)(ws + off); off += 400128;   // N*4 padded to 256
    int* cnt_dst   = (int*)(ws + off); off += 400128;
    const size_t zero_bytes = off;
    // ---- non-zeroed scratch ----
    int* fill      = (int*)(ws + off); off += 400128;   // zeroed by k_coeffs
    int* rowStart  = (int*)(ws + off); off += 400384;   // (N+1)*4 padded
    int* bsum      = (int*)(ws + off); off += 2048;     // NB1*4 padded
    int* esorted   = (int*)(ws + off); off += (size_t)N_EDGES * 4;   // 1.6 MB
    float* agg     = (float*)(ws + off); off += (size_t)N_NODES * D * 4;  // 51.2 MB
    float* c_src   = (float*)(ws + off); off += 400128;
    float* c_dst   = (float*)(ws + off); off += 400128;
    unsigned short* WhiF  = (unsigned short*)(ws + off); off += 32768;
    unsigned short* WloF  = (unsigned short*)(ws + off); off += 32768;
    unsigned short* WrhiF = (unsigned short*)(ws + off); off += 32768;
    unsigned short* WrloF = (unsigned short*)(ws + off); off += 32768;
    float* scale = (float*)(ws + off); off += 512;
    float* shift = (float*)(ws + off); off += 512;
    const size_t needed = off;

    if (ws_size < needed) {
        k_zero_out<<<(N_NODES * D / 4 + 255) / 256, 256, 0, stream>>>(out, N_NODES * D / 4);
        return;
    }

    hipMemsetAsync(d_ws, 0, zero_bytes, stream);

    k_make_frags<<<16, 256, 0, stream>>>(W, Wr, WhiF, WloF, WrhiF, WrloF);
    // ---- counting sort of edges by dst ----
    k_count<<<(N_EDGES + 255) / 256, 256, 0, stream>>>(src, dst, cnt_src, cnt_dst);
    k_coeffs<<<NB1, 256, 0, stream>>>(cnt_src, cnt_dst, c_src, c_dst, fill);
    k_scan1<<<NB1, 256, 0, stream>>>(cnt_dst, rowStart, bsum);
    k_scan2<<<1, 512, 0, stream>>>(bsum, NB1);
    k_scan3<<<NB1, 256, 0, stream>>>(rowStart, bsum);
    k_fill<<<(N_EDGES + 255) / 256, 256, 0, stream>>>(src, dst, rowStart, fill, esorted);
    // ---- segmented gather (replaces atomic scatter; c_dst folded in) ----
    k_gather<<<(N_NODES + 3) / 4, 256, 0, stream>>>(x, esorted, rowStart, c_src, c_dst, agg);
    // pass 1: d_out = relu(agg @ W + b)        (c_dst already applied)
    k_gemm_pass<<<512, 256, 0, stream>>>(agg, (const float*)nullptr, WhiF, WloF, b, out, 0,
                                         (float*)nullptr, (float*)nullptr, N_NODES / 16);
    // pass 2: d_out += relu(x @ Wr + br), collect BN stats
    k_gemm_pass<<<512, 256, 0, stream>>>(x, (const float*)nullptr, WrhiF, WrloF, br, out, 1,
                                         gsum, gsq, N_NODES / 16);
    k_bn_stats<<<1, 128, 0, stream>>>(gsum, gsq, gamma, beta, scale, shift);
    k_bn_apply<<<(N_NODES * D / 4 + 255) / 256, 256, 0, stream>>>(out, scale, shift);
}

// Round 7
// 370.817 us; speedup vs baseline: 1.8790x; 1.2233x over previous
//
#include <hip/hip_runtime.h>

#define N_NODES 100000
#define N_EDGES 400000
#define D 128
#define BN_EPS 1e-5f
#define NTILES 6250   // N_NODES/16

typedef short short8 __attribute__((ext_vector_type(8)));   // 8 bf16 as raw shorts (4 VGPRs)
typedef float f32x4 __attribute__((ext_vector_type(4)));

static __device__ __forceinline__ float bf2f(unsigned short u) {
    unsigned x = ((unsigned)u) << 16;
    return __builtin_bit_cast(float, x);
}
static __device__ __forceinline__ unsigned short f2bf(float f) {
    unsigned x = __builtin_bit_cast(unsigned, f);
    x += 0x7fffu + ((x >> 16) & 1u);   // round-to-nearest-even
    return (unsigned short)(x >> 16);
}
// split f32 into bf16 hi + bf16 lo (a ~= hi + lo, residual ~2^-17 rel)
static __device__ __forceinline__ void splitbf(float a, short& hi, short& lo) {
    unsigned short h = f2bf(a);
    float r = a - bf2f(h);
    hi = (short)h;
    lo = (short)f2bf(r);
}

// ---------------------------------------------------------------- fallback: clean zero-fill of d_out
__global__ void k_zero_out(float* __restrict__ y, int n4) {
    int t = blockIdx.x * blockDim.x + threadIdx.x;
    if (t < n4) ((float4*)y)[t] = float4{0.f, 0.f, 0.f, 0.f};
}

// ---------------------------------------------------------------- degree histograms
__global__ void k_count(const int* __restrict__ src, const int* __restrict__ dst,
                        int* __restrict__ cnt_src, int* __restrict__ cnt_dst) {
    int t = blockIdx.x * blockDim.x + threadIdx.x;
    if (t >= N_EDGES) return;
    atomicAdd(&cnt_src[src[t]], 1);
    atomicAdd(&cnt_dst[dst[t]], 1);
}

// ---------------------------------------------------------------- rsqrt coeffs (+ zero the fill cursors)
__global__ void k_coeffs(const int* __restrict__ cnt_src, const int* __restrict__ cnt_dst,
                         float* __restrict__ c_src, float* __restrict__ c_dst,
                         int* __restrict__ fill) {
    int t = blockIdx.x * blockDim.x + threadIdx.x;
    if (t >= N_NODES) return;
    c_src[t] = rsqrtf(fmaxf((float)cnt_src[t], 1.0f));
    c_dst[t] = rsqrtf(fmaxf((float)cnt_dst[t], 1.0f));
    fill[t] = 0;
}

// ---------------------------------------------------------------- exclusive scan, level 1 (256/block)
__global__ void k_scan1(const int* __restrict__ cnt, int* __restrict__ outp,
                        int* __restrict__ bsum) {
    __shared__ int s[256];
    int i = blockIdx.x * 256 + threadIdx.x;
    int v = (i < N_NODES) ? cnt[i] : 0;
    s[threadIdx.x] = v;
    __syncthreads();
    for (int d = 1; d < 256; d <<= 1) {
        int t = (threadIdx.x >= d) ? s[threadIdx.x - d] : 0;
        __syncthreads();
        s[threadIdx.x] += t;
        __syncthreads();
    }
    if (i < N_NODES) outp[i] = s[threadIdx.x] - v;   // exclusive
    if (threadIdx.x == 255) bsum[blockIdx.x] = s[255];
}

// ---------------------------------------------------------------- exclusive scan, level 2 (single block, nb<=512)
__global__ void k_scan2(int* __restrict__ bsum, int nb) {
    __shared__ int s[512];
    int v = (threadIdx.x < nb) ? bsum[threadIdx.x] : 0;
    s[threadIdx.x] = v;
    __syncthreads();
    for (int d = 1; d < 512; d <<= 1) {
        int t = (threadIdx.x >= d) ? s[threadIdx.x - d] : 0;
        __syncthreads();
        s[threadIdx.x] += t;
        __syncthreads();
    }
    if (threadIdx.x < nb) bsum[threadIdx.x] = s[threadIdx.x] - v;
}

// ---------------------------------------------------------------- scan fixup
__global__ void k_scan3(int* __restrict__ rowStart, const int* __restrict__ boff) {
    int i = blockIdx.x * 256 + threadIdx.x;
    if (i < N_NODES) rowStart[i] += boff[i >> 8];
    if (i == 0) rowStart[N_NODES] = N_EDGES;
}

// ---------------------------------------------------------------- bucket-fill: edge srcs sorted by dst
__global__ void k_fill(const int* __restrict__ src, const int* __restrict__ dst,
                       const int* __restrict__ rowStart, int* __restrict__ fill,
                       int* __restrict__ esorted) {
    int e = blockIdx.x * blockDim.x + threadIdx.x;
    if (e >= N_EDGES) return;
    int d = dst[e];
    int pos = rowStart[d] + atomicAdd(&fill[d], 1);
    esorted[pos] = src[e];
}

// ---------------------------------------------------------------- segmented gather: one wave per node
// agg[n] = c_dst[n] * sum_{e: dst=n} c_src[src_e] * x[src_e]   (written once, no atomics)
__global__ void k_gather(const float* __restrict__ x,
                         const int* __restrict__ esorted, const int* __restrict__ rowStart,
                         const float* __restrict__ c_src, const float* __restrict__ c_dst,
                         float* __restrict__ agg) {
    int n = blockIdx.x * 4 + (threadIdx.x >> 6);
    if (n >= N_NODES) return;
    int lane = threadIdx.x & 63;
    int beg = rowStart[n], end = rowStart[n + 1];
    float a0 = 0.f, a1 = 0.f;
    for (int j = beg; j < end; j++) {
        int s = esorted[j];
        float c = c_src[s];
        float2 pk = ((const float2*)(x + (size_t)s * D))[lane];
        a0 += pk.x * c;
        a1 += pk.y * c;
    }
    float cd = c_dst[n];
    ((float2*)(agg + (size_t)n * D))[lane] = float2{a0 * cd, a1 * cd};
}

// ---------------------------------------------------------------- W(f32) -> MFMA B-fragment order, split hi/lo bf16
// frag layout: fragIdx = ntile*4 + kstep; element j of lane l = W[kstep*32 + (l>>4)*8 + j][ntile*16 + (l&15)]
__global__ void k_make_frags(const float* __restrict__ W,
                             const float* __restrict__ Wr,
                             unsigned short* __restrict__ Whi, unsigned short* __restrict__ Wlo,
                             unsigned short* __restrict__ Wrhi, unsigned short* __restrict__ Wrlo) {
    int t = blockIdx.x * blockDim.x + threadIdx.x;   // 0..4095
    if (t >= 4096) return;
    int mat = t >> 11;
    int fragIdx = (t >> 6) & 31;
    int lane = t & 63;
    int nt = fragIdx >> 2, ks = fragIdx & 3;
    const float* Wsrc = mat ? Wr : W;
    unsigned short* dhi = mat ? Wrhi : Whi;
    unsigned short* dlo = mat ? Wrlo : Wlo;
    int n = nt * 16 + (lane & 15);
    int kbase = ks * 32 + (lane >> 4) * 8;
    short hi[8], lo[8];
#pragma unroll
    for (int j = 0; j < 8; j++) splitbf(Wsrc[(kbase + j) * D + n], hi[j], lo[j]);
    ((uint4*)dhi)[fragIdx * 64 + lane] = *(uint4*)hi;
    ((uint4*)dlo)[fragIdx * 64 + lane] = *(uint4*)lo;
}

// ---------------------------------------------------------------- merged dual GEMM + bias + relu + add + BN stats
// blockIdx.y = column half h (cols h*64 .. h*64+63). y = relu(agg@W+b)+relu(x@Wr+br)
// bf16x3 split precision. y staged in LDS, stored as 256B row segments.
__global__ __launch_bounds__(256, 2) void k_gemm_merged(
    const float* __restrict__ agg,       // [N,128] (c_dst pre-applied)
    const float* __restrict__ x,         // [N,128]
    const unsigned short* __restrict__ Whi, const unsigned short* __restrict__ Wlo,
    const unsigned short* __restrict__ Wrhi, const unsigned short* __restrict__ Wrlo,
    const float* __restrict__ bias_h, const float* __restrict__ bias_r,
    float* __restrict__ yout,
    float* __restrict__ gsum, float* __restrict__ gsq) {
    __shared__ uint4 ldsWh[1024];   // 16 KB : W hi, this col-half
    __shared__ uint4 ldsWl[1024];   // 16 KB : W lo
    __shared__ uint4 ldsRh[1024];   // 16 KB : Wr hi
    __shared__ uint4 ldsRl[1024];   // 16 KB : Wr lo
    __shared__ float ldsY[4][16 * 64];  // 16 KB : per-wave y staging
    const int h = blockIdx.y;
    {
        const uint4* gwh = (const uint4*)Whi + h * 1024;
        const uint4* gwl = (const uint4*)Wlo + h * 1024;
        const uint4* grh = (const uint4*)Wrhi + h * 1024;
        const uint4* grl = (const uint4*)Wrlo + h * 1024;
        for (int i = threadIdx.x; i < 1024; i += 256) {
            ldsWh[i] = gwh[i];
            ldsWl[i] = gwl[i];
            ldsRh[i] = grh[i];
            ldsRl[i] = grl[i];
        }
    }
    __syncthreads();

    const int wave = threadIdx.x >> 6;
    const int lane = threadIdx.x & 63;
    const int quad = lane >> 4;
    const int l16 = lane & 15;

    float bh[4], brr[4];
#pragma unroll
    for (int ntl = 0; ntl < 4; ntl++) {
        int col = h * 64 + ntl * 16 + l16;
        bh[ntl] = bias_h[col];
        brr[ntl] = bias_r[col];
    }

    float s_acc[4] = {0.f, 0.f, 0.f, 0.f}, q_acc[4] = {0.f, 0.f, 0.f, 0.f};
    const int gwid = blockIdx.x * 4 + wave;
    const int nW = gridDim.x * 4;
    float* Yw = ldsY[wave];
    const float4* Yf4 = (const float4*)Yw;

    for (int rt = gwid; rt < NTILES; rt += nW) {
        const int rowbase = rt * 16;
        const int arow = rowbase + l16;
        const float4* ap = (const float4*)(agg + (size_t)arow * D + quad * 8);
        const float4* xp = (const float4*)(x + (size_t)arow * D + quad * 8);

        // ---- issue all 16 loads up front
        float4 ra[8], rx[8];
#pragma unroll
        for (int ks = 0; ks < 4; ks++) {
            ra[ks * 2] = ap[ks * 8];
            ra[ks * 2 + 1] = ap[ks * 8 + 1];
            rx[ks * 2] = xp[ks * 8];
            rx[ks * 2 + 1] = xp[ks * 8 + 1];
        }

        // ---- split into hi/lo bf16 fragments
        short8 aH[4], aL[4], xH[4], xL[4];
#pragma unroll
        for (int ks = 0; ks < 4; ks++) {
            float va[8] = {ra[ks * 2].x, ra[ks * 2].y, ra[ks * 2].z, ra[ks * 2].w,
                           ra[ks * 2 + 1].x, ra[ks * 2 + 1].y, ra[ks * 2 + 1].z, ra[ks * 2 + 1].w};
            float vx[8] = {rx[ks * 2].x, rx[ks * 2].y, rx[ks * 2].z, rx[ks * 2].w,
                           rx[ks * 2 + 1].x, rx[ks * 2 + 1].y, rx[ks * 2 + 1].z, rx[ks * 2 + 1].w};
            short8 h1, l1, h2, l2;
#pragma unroll
            for (int j = 0; j < 8; j++) {
                short hh, ll;
                splitbf(va[j], hh, ll);
                h1[j] = hh; l1[j] = ll;
                splitbf(vx[j], hh, ll);
                h2[j] = hh; l2[j] = ll;
            }
            aH[ks] = h1; aL[ks] = l1;
            xH[ks] = h2; xL[ks] = l2;
        }

        // ---- MFMA: 4 local n-tiles x 4 k-steps x 3 split-terms x 2 matrices
        f32x4 accH[4], accR[4];
#pragma unroll
        for (int ntl = 0; ntl < 4; ntl++) {
            accH[ntl] = f32x4{0.f, 0.f, 0.f, 0.f};
            accR[ntl] = f32x4{0.f, 0.f, 0.f, 0.f};
#pragma unroll
            for (int ks = 0; ks < 4; ks++) {
                const int fi = (ntl * 4 + ks) * 64 + lane;
                short8 wh = __builtin_bit_cast(short8, ldsWh[fi]);
                short8 wl = __builtin_bit_cast(short8, ldsWl[fi]);
                short8 rh = __builtin_bit_cast(short8, ldsRh[fi]);
                short8 rl = __builtin_bit_cast(short8, ldsRl[fi]);
                accH[ntl] = __builtin_amdgcn_mfma_f32_16x16x32_bf16(aH[ks], wh, accH[ntl], 0, 0, 0);
                accH[ntl] = __builtin_amdgcn_mfma_f32_16x16x32_bf16(aH[ks], wl, accH[ntl], 0, 0, 0);
                accH[ntl] = __builtin_amdgcn_mfma_f32_16x16x32_bf16(aL[ks], wh, accH[ntl], 0, 0, 0);
                accR[ntl] = __builtin_amdgcn_mfma_f32_16x16x32_bf16(xH[ks], rh, accR[ntl], 0, 0, 0);
                accR[ntl] = __builtin_amdgcn_mfma_f32_16x16x32_bf16(xH[ks], rl, accR[ntl], 0, 0, 0);
                accR[ntl] = __builtin_amdgcn_mfma_f32_16x16x32_bf16(xL[ks], rh, accR[ntl], 0, 0, 0);
            }
        }

        // ---- epilogue: y -> LDS patch + BN partials
#pragma unroll
        for (int ntl = 0; ntl < 4; ntl++) {
            float s = 0.f, q = 0.f;
#pragma unroll
            for (int r = 0; r < 4; r++) {
                float y = fmaxf(accH[ntl][r] + bh[ntl], 0.f) + fmaxf(accR[ntl][r] + brr[ntl], 0.f);
                Yw[(quad * 4 + r) * 64 + ntl * 16 + l16] = y;
                s += y;
                q += y * y;
            }
            s_acc[ntl] += s;
            q_acc[ntl] += q;
        }
        // ---- coalesced store: 4 rows x 256 B contiguous per instruction
#pragma unroll
        for (int j = 0; j < 4; j++) {
            int row = j * 4 + (lane >> 4);
            float4 v = Yf4[row * 16 + l16];
            ((float4*)(yout + (size_t)(rowbase + row) * D + h * 64))[l16] = v;
        }
    }

    // ---- per-wave stats: quads hold same column set
#pragma unroll
    for (int ntl = 0; ntl < 4; ntl++) {
        float s = s_acc[ntl], q = q_acc[ntl];
        s += __shfl_xor(s, 16, 64);
        s += __shfl_xor(s, 32, 64);
        q += __shfl_xor(q, 16, 64);
        q += __shfl_xor(q, 32, 64);
        if (lane < 16) {
            unsafeAtomicAdd(&gsum[h * 64 + ntl * 16 + lane], s);
            unsafeAtomicAdd(&gsq[h * 64 + ntl * 16 + lane], q);
        }
    }
}

// ---------------------------------------------------------------- BN stats -> scale/shift (f32)
__global__ void k_bn_stats(const float* __restrict__ gsum, const float* __restrict__ gsq,
                           const float* __restrict__ gamma, const float* __restrict__ beta,
                           float* __restrict__ scale, float* __restrict__ shift) {
    int f = threadIdx.x;   // 128 threads
    const float invN = 1.0f / (float)N_NODES;
    float mean = gsum[f] * invN;
    float var = fmaxf(gsq[f] * invN - mean * mean, 0.f);
    float sc = gamma[f] * rsqrtf(var + BN_EPS);
    scale[f] = sc;
    shift[f] = beta[f] - mean * sc;
}

// ---------------------------------------------------------------- apply BN in-place on d_out (f32)
__global__ void k_bn_apply(float* __restrict__ y,
                           const float* __restrict__ scale, const float* __restrict__ shift) {
    int t = blockIdx.x * blockDim.x + threadIdx.x;
    const int total4 = N_NODES * D / 4;
    if (t >= total4) return;
    float4 v = ((float4*)y)[t];
    int f = (t * 4) & (D - 1);
    v.x = v.x * scale[f] + shift[f];
    v.y = v.y * scale[f + 1] + shift[f + 1];
    v.z = v.z * scale[f + 2] + shift[f + 2];
    v.w = v.w * scale[f + 3] + shift[f + 3];
    ((float4*)y)[t] = v;
}

// ---------------------------------------------------------------- launch
extern "C" void kernel_launch(void* const* d_in, const int* in_sizes, int n_in,
                              void* d_out, int out_size, void* d_ws, size_t ws_size,
                              hipStream_t stream) {
    const float* x     = (const float*)d_in[0];   // node_feats f32 [N,128]
    const float* W     = (const float*)d_in[1];
    const float* b     = (const float*)d_in[2];
    const float* Wr    = (const float*)d_in[3];
    const float* br    = (const float*)d_in[4];
    const float* gamma = (const float*)d_in[5];
    const float* beta  = (const float*)d_in[6];
    const int* src = (const int*)d_in[7];
    const int* dst = (const int*)d_in[8];
    float* out = (float*)d_out;

    const int NB1 = (N_NODES + 255) / 256;   // 391 scan blocks

    char* ws = (char*)d_ws;
    size_t off = 0;
    // ---- zeroed prefix (one contiguous memset, ~0.8 MB) ----
    float* gsum    = (float*)(ws + off); off += 512;
    float* gsq     = (float*)(ws + off); off += 512;
    int* cnt_src   = (int*)(ws + off); off += 400128;   // N*4 padded to 256
    int* cnt_dst   = (int*)(ws + off); off += 400128;
    const size_t zero_bytes = off;
    // ---- non-zeroed scratch ----
    int* fill      = (int*)(ws + off); off += 400128;   // zeroed by k_coeffs
    int* rowStart  = (int*)(ws + off); off += 400384;   // (N+1)*4 padded
    int* bsum      = (int*)(ws + off); off += 2048;     // NB1*4 padded
    int* esorted   = (int*)(ws + off); off += (size_t)N_EDGES * 4;   // 1.6 MB
    float* agg     = (float*)(ws + off); off += (size_t)N_NODES * D * 4;  // 51.2 MB
    float* c_src   = (float*)(ws + off); off += 400128;
    float* c_dst   = (float*)(ws + off); off += 400128;
    unsigned short* WhiF  = (unsigned short*)(ws + off); off += 32768;
    unsigned short* WloF  = (unsigned short*)(ws + off); off += 32768;
    unsigned short* WrhiF = (unsigned short*)(ws + off); off += 32768;
    unsigned short* WrloF = (unsigned short*)(ws + off); off += 32768;
    float* scale = (float*)(ws + off); off += 512;
    float* shift = (float*)(ws + off); off += 512;
    const size_t needed = off;

    if (ws_size < needed) {
        k_zero_out<<<(N_NODES * D / 4 + 255) / 256, 256, 0, stream>>>(out, N_NODES * D / 4);
        return;
    }

    hipMemsetAsync(d_ws, 0, zero_bytes, stream);

    k_make_frags<<<16, 256, 0, stream>>>(W, Wr, WhiF, WloF, WrhiF, WrloF);
    // ---- counting sort of edges by dst ----
    k_count<<<(N_EDGES + 255) / 256, 256, 0, stream>>>(src, dst, cnt_src, cnt_dst);
    k_coeffs<<<NB1, 256, 0, stream>>>(cnt_src, cnt_dst, c_src, c_dst, fill);
    k_scan1<<<NB1, 256, 0, stream>>>(cnt_dst, rowStart, bsum);
    k_scan2<<<1, 512, 0, stream>>>(bsum, NB1);
    k_scan3<<<NB1, 256, 0, stream>>>(rowStart, bsum);
    k_fill<<<(N_EDGES + 255) / 256, 256, 0, stream>>>(src, dst, rowStart, fill, esorted);
    // ---- segmented gather (c_dst folded in) ----
    k_gather<<<(N_NODES + 3) / 4, 256, 0, stream>>>(x, esorted, rowStart, c_src, c_dst, agg);
    // ---- merged dual GEMM + relu + add + BN partials ----
    k_gemm_merged<<<dim3(256, 2), 256, 0, stream>>>(agg, x, WhiF, WloF, WrhiF, WrloF,
                                                    b, br, out, gsum, gsq);
    k_bn_stats<<<1, 128, 0, stream>>>(gsum, gsq, gamma, beta, scale, shift);
    k_bn_apply<<<(N_NODES * D / 4 + 255) / 256, 256, 0, stream>>>(out, scale, shift);
}

// Round 8
// 321.187 us; speedup vs baseline: 2.1693x; 1.1545x over previous
//
#include <hip/hip_runtime.h>

#define N_NODES 100000
#define N_EDGES 400000
#define D 128
#define BN_EPS 1e-5f
#define NTILES 6250   // N_NODES/16

typedef short short8 __attribute__((ext_vector_type(8)));   // 8 bf16 as raw shorts (4 VGPRs)
typedef float f32x4 __attribute__((ext_vector_type(4)));

static __device__ __forceinline__ float bf2f(unsigned short u) {
    unsigned x = ((unsigned)u) << 16;
    return __builtin_bit_cast(float, x);
}
static __device__ __forceinline__ unsigned short f2bf(float f) {
    unsigned x = __builtin_bit_cast(unsigned, f);
    x += 0x7fffu + ((x >> 16) & 1u);   // round-to-nearest-even
    return (unsigned short)(x >> 16);
}
// split f32 into bf16 hi + bf16 lo (a ~= hi + lo, residual ~2^-17 rel)
static __device__ __forceinline__ void splitbf(float a, short& hi, short& lo) {
    unsigned short h = f2bf(a);
    float r = a - bf2f(h);
    hi = (short)h;
    lo = (short)f2bf(r);
}

// ---------------------------------------------------------------- fallback: clean zero-fill of d_out
__global__ void k_zero_out(float* __restrict__ y, int n4) {
    int t = blockIdx.x * blockDim.x + threadIdx.x;
    if (t < n4) ((float4*)y)[t] = float4{0.f, 0.f, 0.f, 0.f};
}

// ---------------------------------------------------------------- degree histograms
__global__ void k_count(const int* __restrict__ src, const int* __restrict__ dst,
                        int* __restrict__ cnt_src, int* __restrict__ cnt_dst) {
    int t = blockIdx.x * blockDim.x + threadIdx.x;
    if (t >= N_EDGES) return;
    atomicAdd(&cnt_src[src[t]], 1);
    atomicAdd(&cnt_dst[dst[t]], 1);
}

// ---------------------------------------------------------------- rsqrt coeffs (+ zero the fill cursors)
__global__ void k_coeffs(const int* __restrict__ cnt_src, const int* __restrict__ cnt_dst,
                         float* __restrict__ c_src, float* __restrict__ c_dst,
                         int* __restrict__ fill) {
    int t = blockIdx.x * blockDim.x + threadIdx.x;
    if (t >= N_NODES) return;
    c_src[t] = rsqrtf(fmaxf((float)cnt_src[t], 1.0f));
    c_dst[t] = rsqrtf(fmaxf((float)cnt_dst[t], 1.0f));
    fill[t] = 0;
}

// ---------------------------------------------------------------- exclusive scan, level 1 (256/block)
__global__ void k_scan1(const int* __restrict__ cnt, int* __restrict__ outp,
                        int* __restrict__ bsum) {
    __shared__ int s[256];
    int i = blockIdx.x * 256 + threadIdx.x;
    int v = (i < N_NODES) ? cnt[i] : 0;
    s[threadIdx.x] = v;
    __syncthreads();
    for (int d = 1; d < 256; d <<= 1) {
        int t = (threadIdx.x >= d) ? s[threadIdx.x - d] : 0;
        __syncthreads();
        s[threadIdx.x] += t;
        __syncthreads();
    }
    if (i < N_NODES) outp[i] = s[threadIdx.x] - v;   // exclusive
    if (threadIdx.x == 255) bsum[blockIdx.x] = s[255];
}

// ---------------------------------------------------------------- exclusive scan, level 2 (single block, nb<=512)
__global__ void k_scan2(int* __restrict__ bsum, int nb) {
    __shared__ int s[512];
    int v = (threadIdx.x < nb) ? bsum[threadIdx.x] : 0;
    s[threadIdx.x] = v;
    __syncthreads();
    for (int d = 1; d < 512; d <<= 1) {
        int t = (threadIdx.x >= d) ? s[threadIdx.x - d] : 0;
        __syncthreads();
        s[threadIdx.x] += t;
        __syncthreads();
    }
    if (threadIdx.x < nb) bsum[threadIdx.x] = s[threadIdx.x] - v;
}

// ---------------------------------------------------------------- scan fixup
__global__ void k_scan3(int* __restrict__ rowStart, const int* __restrict__ boff) {
    int i = blockIdx.x * 256 + threadIdx.x;
    if (i < N_NODES) rowStart[i] += boff[i >> 8];
    if (i == 0) rowStart[N_NODES] = N_EDGES;
}

// ---------------------------------------------------------------- bucket-fill: edge srcs sorted by dst
__global__ void k_fill(const int* __restrict__ src, const int* __restrict__ dst,
                       const int* __restrict__ rowStart, int* __restrict__ fill,
                       int* __restrict__ esorted) {
    int e = blockIdx.x * blockDim.x + threadIdx.x;
    if (e >= N_EDGES) return;
    int d = dst[e];
    int pos = rowStart[d] + atomicAdd(&fill[d], 1);
    esorted[pos] = src[e];
}

// ---------------------------------------------------------------- segmented gather: one wave per node
// aggS[n] = split-bf16 of c_dst[n] * sum c_src[s]*x[s] : 128 hi shorts then 128 lo shorts (512B/row)
__global__ void k_gather(const float* __restrict__ x,
                         const int* __restrict__ esorted, const int* __restrict__ rowStart,
                         const float* __restrict__ c_src, const float* __restrict__ c_dst,
                         unsigned short* __restrict__ aggS) {
    int n = blockIdx.x * 4 + (threadIdx.x >> 6);
    if (n >= N_NODES) return;
    int lane = threadIdx.x & 63;
    int beg = rowStart[n], end = rowStart[n + 1];
    float a0 = 0.f, a1 = 0.f;
    for (int j = beg; j < end; j++) {
        int s = esorted[j];
        float c = c_src[s];
        float2 pk = ((const float2*)(x + (size_t)s * D))[lane];
        a0 += pk.x * c;
        a1 += pk.y * c;
    }
    float cd = c_dst[n];
    a0 *= cd; a1 *= cd;
    short h0, l0, h1, l1;
    splitbf(a0, h0, l0);
    splitbf(a1, h1, l1);
    unsigned hi = (unsigned)(unsigned short)h0 | ((unsigned)(unsigned short)h1 << 16);
    unsigned lo = (unsigned)(unsigned short)l0 | ((unsigned)(unsigned short)l1 << 16);
    unsigned* base = (unsigned*)(aggS + (size_t)n * 256);
    base[lane] = hi;        // bytes [0,256): hi plane
    base[64 + lane] = lo;   // bytes [256,512): lo plane
}

// ---------------------------------------------------------------- W(f32) -> MFMA B-fragment order, split hi/lo bf16
// frag layout: fragIdx = ntile*4 + kstep; element j of lane l = W[kstep*32 + (l>>4)*8 + j][ntile*16 + (l&15)]
__global__ void k_make_frags(const float* __restrict__ W,
                             const float* __restrict__ Wr,
                             unsigned short* __restrict__ Whi, unsigned short* __restrict__ Wlo,
                             unsigned short* __restrict__ Wrhi, unsigned short* __restrict__ Wrlo) {
    int t = blockIdx.x * blockDim.x + threadIdx.x;   // 0..4095
    if (t >= 4096) return;
    int mat = t >> 11;
    int fragIdx = (t >> 6) & 31;
    int lane = t & 63;
    int nt = fragIdx >> 2, ks = fragIdx & 3;
    const float* Wsrc = mat ? Wr : W;
    unsigned short* dhi = mat ? Wrhi : Whi;
    unsigned short* dlo = mat ? Wrlo : Wlo;
    int n = nt * 16 + (lane & 15);
    int kbase = ks * 32 + (lane >> 4) * 8;
    short hi[8], lo[8];
#pragma unroll
    for (int j = 0; j < 8; j++) splitbf(Wsrc[(kbase + j) * D + n], hi[j], lo[j]);
    ((uint4*)dhi)[fragIdx * 64 + lane] = *(uint4*)hi;
    ((uint4*)dlo)[fragIdx * 64 + lane] = *(uint4*)lo;
}

// ---------------------------------------------------------------- merged dual GEMM, weights-in-VGPR
// block = 4 waves; wave w owns cols [w*32, w*32+32). All waves share each 16-row tile;
// y staged in one LDS tile, stored as full 512B rows. bf16x3 split precision.
__global__ __launch_bounds__(256, 2) void k_gemm_merged(
    const unsigned short* __restrict__ aggS,   // [N][256] shorts: hi|lo planes
    const float* __restrict__ x,               // [N,128] f32
    const unsigned short* __restrict__ Whi, const unsigned short* __restrict__ Wlo,
    const unsigned short* __restrict__ Wrhi, const unsigned short* __restrict__ Wrlo,
    const float* __restrict__ bias_h, const float* __restrict__ bias_r,
    float* __restrict__ yout,
    float* __restrict__ gsum, float* __restrict__ gsq) {
    __shared__ float Y[16 * 132];   // 8.4 KB, +4 pad breaks quad bank aliasing

    const int wave = threadIdx.x >> 6;
    const int lane = threadIdx.x & 63;
    const int quad = lane >> 4;
    const int l16 = lane & 15;

    // ---- preload this wave's 32-col weight frags into VGPRs (8 frags x 4 sets)
    short8 wHf[8], wLf[8], rHf[8], rLf[8];
#pragma unroll
    for (int f = 0; f < 8; f++) {
        int nt = wave * 2 + (f >> 2), ks = f & 3;
        int gi = (nt * 4 + ks) * 64 + lane;
        wHf[f] = __builtin_bit_cast(short8, ((const uint4*)Whi)[gi]);
        wLf[f] = __builtin_bit_cast(short8, ((const uint4*)Wlo)[gi]);
        rHf[f] = __builtin_bit_cast(short8, ((const uint4*)Wrhi)[gi]);
        rLf[f] = __builtin_bit_cast(short8, ((const uint4*)Wrlo)[gi]);
    }
    float bh[2], brr[2];
#pragma unroll
    for (int ntl = 0; ntl < 2; ntl++) {
        int col = wave * 32 + ntl * 16 + l16;
        bh[ntl] = bias_h[col];
        brr[ntl] = bias_r[col];
    }

    float s_acc[2] = {0.f, 0.f}, q_acc[2] = {0.f, 0.f};

    for (int rt = blockIdx.x; rt < NTILES; rt += gridDim.x) {
        const int rowbase = rt * 16;
        const int arow = rowbase + l16;

        // ---- agg frags: direct uint4 loads (pre-split by k_gather)
        short8 aH[4], aL[4];
        const uint4* agp = (const uint4*)(aggS + (size_t)arow * 256);
#pragma unroll
        for (int ks = 0; ks < 4; ks++) {
            aH[ks] = __builtin_bit_cast(short8, agp[ks * 4 + quad]);
            aL[ks] = __builtin_bit_cast(short8, agp[16 + ks * 4 + quad]);
        }
        // ---- x: load f32, split in-register
        float4 rx[8];
        const float4* xp = (const float4*)(x + (size_t)arow * D + quad * 8);
#pragma unroll
        for (int ks = 0; ks < 4; ks++) {
            rx[ks * 2] = xp[ks * 8];
            rx[ks * 2 + 1] = xp[ks * 8 + 1];
        }
        short8 xH[4], xL[4];
#pragma unroll
        for (int ks = 0; ks < 4; ks++) {
            float v[8] = {rx[ks * 2].x, rx[ks * 2].y, rx[ks * 2].z, rx[ks * 2].w,
                          rx[ks * 2 + 1].x, rx[ks * 2 + 1].y, rx[ks * 2 + 1].z, rx[ks * 2 + 1].w};
            short8 h, l;
#pragma unroll
            for (int j = 0; j < 8; j++) {
                short hh, ll;
                splitbf(v[j], hh, ll);
                h[j] = hh; l[j] = ll;
            }
            xH[ks] = h; xL[ks] = l;
        }

        // ---- MFMA: 2 ntiles x 4 ks x (3 split-terms x 2 matrices)
        f32x4 accH[2], accR[2];
#pragma unroll
        for (int ntl = 0; ntl < 2; ntl++) {
            accH[ntl] = f32x4{0.f, 0.f, 0.f, 0.f};
            accR[ntl] = f32x4{0.f, 0.f, 0.f, 0.f};
#pragma unroll
            for (int ks = 0; ks < 4; ks++) {
                const int f = ntl * 4 + ks;
                accH[ntl] = __builtin_amdgcn_mfma_f32_16x16x32_bf16(aH[ks], wHf[f], accH[ntl], 0, 0, 0);
                accH[ntl] = __builtin_amdgcn_mfma_f32_16x16x32_bf16(aH[ks], wLf[f], accH[ntl], 0, 0, 0);
                accH[ntl] = __builtin_amdgcn_mfma_f32_16x16x32_bf16(aL[ks], wHf[f], accH[ntl], 0, 0, 0);
                accR[ntl] = __builtin_amdgcn_mfma_f32_16x16x32_bf16(xH[ks], rHf[f], accR[ntl], 0, 0, 0);
                accR[ntl] = __builtin_amdgcn_mfma_f32_16x16x32_bf16(xH[ks], rLf[f], accR[ntl], 0, 0, 0);
                accR[ntl] = __builtin_amdgcn_mfma_f32_16x16x32_bf16(xL[ks], rHf[f], accR[ntl], 0, 0, 0);
            }
        }

        // ---- epilogue: y -> shared LDS tile + BN partials
#pragma unroll
        for (int ntl = 0; ntl < 2; ntl++) {
            float s = 0.f, q = 0.f;
#pragma unroll
            for (int r = 0; r < 4; r++) {
                float y = fmaxf(accH[ntl][r] + bh[ntl], 0.f) + fmaxf(accR[ntl][r] + brr[ntl], 0.f);
                Y[(quad * 4 + r) * 132 + wave * 32 + ntl * 16 + l16] = y;
                s += y;
                q += y * y;
            }
            s_acc[ntl] += s;
            q_acc[ntl] += q;
        }
        __syncthreads();
        // ---- store full 512B rows: 32 threads x float4 per row
#pragma unroll
        for (int j = 0; j < 2; j++) {
            int t = threadIdx.x + j * 256;
            int row = t >> 5, c4 = t & 31;
            float4 v = *(const float4*)&Y[row * 132 + c4 * 4];
            ((float4*)(yout + (size_t)(rowbase + row) * D))[c4] = v;
        }
        __syncthreads();
    }

    // ---- per-wave stats: quads hold same column set
#pragma unroll
    for (int ntl = 0; ntl < 2; ntl++) {
        float s = s_acc[ntl], q = q_acc[ntl];
        s += __shfl_xor(s, 16, 64);
        s += __shfl_xor(s, 32, 64);
        q += __shfl_xor(q, 16, 64);
        q += __shfl_xor(q, 32, 64);
        if (lane < 16) {
            unsafeAtomicAdd(&gsum[wave * 32 + ntl * 16 + lane], s);
            unsafeAtomicAdd(&gsq[wave * 32 + ntl * 16 + lane], q);
        }
    }
}

// ---------------------------------------------------------------- BN stats -> scale/shift (f32)
__global__ void k_bn_stats(const float* __restrict__ gsum, const float* __restrict__ gsq,
                           const float* __restrict__ gamma, const float* __restrict__ beta,
                           float* __restrict__ scale, float* __restrict__ shift) {
    int f = threadIdx.x;   // 128 threads
    const float invN = 1.0f / (float)N_NODES;
    float mean = gsum[f] * invN;
    float var = fmaxf(gsq[f] * invN - mean * mean, 0.f);
    float sc = gamma[f] * rsqrtf(var + BN_EPS);
    scale[f] = sc;
    shift[f] = beta[f] - mean * sc;
}

// ---------------------------------------------------------------- apply BN in-place on d_out (f32)
__global__ void k_bn_apply(float* __restrict__ y,
                           const float* __restrict__ scale, const float* __restrict__ shift) {
    int t = blockIdx.x * blockDim.x + threadIdx.x;
    const int total4 = N_NODES * D / 4;
    if (t >= total4) return;
    float4 v = ((float4*)y)[t];
    int f = (t * 4) & (D - 1);
    v.x = v.x * scale[f] + shift[f];
    v.y = v.y * scale[f + 1] + shift[f + 1];
    v.z = v.z * scale[f + 2] + shift[f + 2];
    v.w = v.w * scale[f + 3] + shift[f + 3];
    ((float4*)y)[t] = v;
}

// ---------------------------------------------------------------- launch
extern "C" void kernel_launch(void* const* d_in, const int* in_sizes, int n_in,
                              void* d_out, int out_size, void* d_ws, size_t ws_size,
                              hipStream_t stream) {
    const float* x     = (const float*)d_in[0];   // node_feats f32 [N,128]
    const float* W     = (const float*)d_in[1];
    const float* b     = (const float*)d_in[2];
    const float* Wr    = (const float*)d_in[3];
    const float* br    = (const float*)d_in[4];
    const float* gamma = (const float*)d_in[5];
    const float* beta  = (const float*)d_in[6];
    const int* src = (const int*)d_in[7];
    const int* dst = (const int*)d_in[8];
    float* out = (float*)d_out;

    const int NB1 = (N_NODES + 255) / 256;   // 391 scan blocks

    char* ws = (char*)d_ws;
    size_t off = 0;
    // ---- zeroed prefix (one contiguous memset, ~0.8 MB) ----
    float* gsum    = (float*)(ws + off); off += 512;
    float* gsq     = (float*)(ws + off); off += 512;
    int* cnt_src   = (int*)(ws + off); off += 400128;   // N*4 padded to 256
    int* cnt_dst   = (int*)(ws + off); off += 400128;
    const size_t zero_bytes = off;
    // ---- non-zeroed scratch ----
    int* fill      = (int*)(ws + off); off += 400128;   // zeroed by k_coeffs
    int* rowStart  = (int*)(ws + off); off += 400384;   // (N+1)*4 padded
    int* bsum      = (int*)(ws + off); off += 2048;     // NB1*4 padded
    int* esorted   = (int*)(ws + off); off += (size_t)N_EDGES * 4;   // 1.6 MB
    unsigned short* aggS = (unsigned short*)(ws + off); off += (size_t)N_NODES * 512;  // 51.2 MB
    float* c_src   = (float*)(ws + off); off += 400128;
    float* c_dst   = (float*)(ws + off); off += 400128;
    unsigned short* WhiF  = (unsigned short*)(ws + off); off += 32768;
    unsigned short* WloF  = (unsigned short*)(ws + off); off += 32768;
    unsigned short* WrhiF = (unsigned short*)(ws + off); off += 32768;
    unsigned short* WrloF = (unsigned short*)(ws + off); off += 32768;
    float* scale = (float*)(ws + off); off += 512;
    float* shift = (float*)(ws + off); off += 512;
    const size_t needed = off;

    if (ws_size < needed) {
        k_zero_out<<<(N_NODES * D / 4 + 255) / 256, 256, 0, stream>>>(out, N_NODES * D / 4);
        return;
    }

    hipMemsetAsync(d_ws, 0, zero_bytes, stream);

    k_make_frags<<<16, 256, 0, stream>>>(W, Wr, WhiF, WloF, WrhiF, WrloF);
    // ---- counting sort of edges by dst ----
    k_count<<<(N_EDGES + 255) / 256, 256, 0, stream>>>(src, dst, cnt_src, cnt_dst);
    k_coeffs<<<NB1, 256, 0, stream>>>(cnt_src, cnt_dst, c_src, c_dst, fill);
    k_scan1<<<NB1, 256, 0, stream>>>(cnt_dst, rowStart, bsum);
    k_scan2<<<1, 512, 0, stream>>>(bsum, NB1);
    k_scan3<<<NB1, 256, 0, stream>>>(rowStart, bsum);
    k_fill<<<(N_EDGES + 255) / 256, 256, 0, stream>>>(src, dst, rowStart, fill, esorted);
    // ---- segmented gather (c_dst folded in, emits split bf16 hi|lo) ----
    k_gather<<<(N_NODES + 3) / 4, 256, 0, stream>>>(x, esorted, rowStart, c_src, c_dst, aggS);
    // ---- merged dual GEMM + relu + add + BN partials ----
    k_gemm_merged<<<512, 256, 0, stream>>>(aggS, x, WhiF, WloF, WrhiF, WrloF,
                                           b, br, out, gsum, gsq);
    k_bn_stats<<<1, 128, 0, stream>>>(gsum, gsq, gamma, beta, scale, shift);
    k_bn_apply<<<(N_NODES * D / 4 + 255) / 256, 256, 0, stream>>>(out, scale, shift);
}